// Round 7
// baseline (67027.991 us; speedup 1.0000x reference)
//
#include <hip/hip_runtime.h>
#include <cstdint>
#include <cstddef>

#define TPB 1024
#define NB  256

typedef float4 f4;
typedef float f32x4 __attribute__((ext_vector_type(4)));
typedef short short8 __attribute__((ext_vector_type(8)));

// ---------------- ws float offsets ----------------
#define O_SLOT   0         // uint slots[256][16] + go flag (4352 floats reserved)
#define O_AH     4352      // f32 [16][1024]
#define O_AC     20736
#define O_DH     37120
#define O_DC     53504
#define O_ACTX   69888     // f32 [2][16][512]
#define O_AW     86272     // f32 [16][256]
#define O_AWC    90368
#define O_XU     94464     // bf16 [2][320 k8][16 b][8 e]  (actx 0..63 | ah 64..191 | dh 192..319)
#define O_DECFR  135424    // bf16 [200][32][16][8]
#define O_PMEM   545024    // f32 [4096][128]
#define O_LDWBF  1069312   // bf16 [128][32]
#define O_CONVWT 1071360   // f32 [62][32]
#define ZERO_BYTES (O_DECFR * 4)   // zero: slots/go + f32 state + both xU parities

#define XU_PAR  40960      // shorts per parity copy

// LDS weight-row swizzle (T2): 16B-granular XOR, bijective (row lengths % 64 == 0)
#define SWZ(n, k) ((k) ^ (((n) & 7) << 3))

// ---------------- JAX Threefry-2x32 (partitionable) ----------------
__device__ __forceinline__ void tf2x32(uint32_t k0, uint32_t k1, uint32_t x0, uint32_t x1,
                                       uint32_t& o0, uint32_t& o1) {
  uint32_t ks2 = k0 ^ k1 ^ 0x1BD11BDAu;
  x0 += k0; x1 += k1;
#define TFR(r) { x0 += x1; x1 = (x1 << (r)) | (x1 >> (32 - (r))); x1 ^= x0; }
  TFR(13) TFR(15) TFR(26) TFR(6)
  x0 += k1;  x1 += ks2 + 1u;
  TFR(17) TFR(29) TFR(16) TFR(24)
  x0 += ks2; x1 += k0 + 2u;
  TFR(13) TFR(15) TFR(26) TFR(6)
  x0 += k0;  x1 += k1 + 3u;
  TFR(17) TFR(29) TFR(16) TFR(24)
  x0 += k1;  x1 += ks2 + 4u;
  TFR(13) TFR(15) TFR(26) TFR(6)
  x0 += ks2; x1 += k0 + 5u;
#undef TFR
  o0 = x0; o1 = x1;
}
__device__ __forceinline__ uint32_t tf_fold(uint32_t k0, uint32_t k1, uint32_t idx) {
  uint32_t a, b; tf2x32(k0, k1, 0u, idx, a, b); return a ^ b;
}

// ---------------- helpers ----------------
__device__ __forceinline__ unsigned short f2bf(float x) {   // RNE fp32->bf16
  uint32_t u = __float_as_uint(x);
  u += 0x7fffu + ((u >> 16) & 1u);
  return (unsigned short)(u >> 16);
}
__device__ __forceinline__ float dot4(f4 a, f4 b, float acc) {
  acc = fmaf(a.x, b.x, acc); acc = fmaf(a.y, b.y, acc);
  acc = fmaf(a.z, b.z, acc); acc = fmaf(a.w, b.w, acc);
  return acc;
}
__device__ __forceinline__ float dot_f4(const float* __restrict__ x, const float* __restrict__ w, int n4) {
  const f4* xv = (const f4*)x; const f4* wv = (const f4*)w;
  float s = 0.f;
#pragma unroll 8
  for (int k = 0; k < n4; ++k) s = dot4(xv[k], wv[k], s);
  return s;
}
__device__ __forceinline__ float sigm(float x) { return 1.f / (1.f + expf(-x)); }
__device__ __forceinline__ float wave_sum(float s) {
#pragma unroll
  for (int off = 32; off; off >>= 1) s += __shfl_xor(s, off, 64);
  return s;
}
__device__ __forceinline__ float wave_max(float s) {
#pragma unroll
  for (int off = 32; off; off >>= 1) s = fmaxf(s, __shfl_xor(s, off, 64));
  return s;
}

// Distributed grid barrier: per-block arrival slots (64B apart) + block0 aggregator + go flag.
// No same-address RMW contention anywhere.
__device__ __forceinline__ void grid_sync(unsigned* slots, unsigned epoch, int tid, int bid) {
  unsigned* go = slots + NB * 16;
  __syncthreads();
  if (bid == 0) {
    if (tid == 0) {
      __threadfence();
      __hip_atomic_store(slots, epoch, __ATOMIC_RELEASE, __HIP_MEMORY_SCOPE_AGENT);
    }
    if (tid < NB) {
      while (__hip_atomic_load(slots + tid * 16, __ATOMIC_ACQUIRE, __HIP_MEMORY_SCOPE_AGENT) < epoch)
        __builtin_amdgcn_s_sleep(1);
    }
    __syncthreads();
    if (tid == 0)
      __hip_atomic_store(go, epoch, __ATOMIC_RELEASE, __HIP_MEMORY_SCOPE_AGENT);
  } else {
    if (tid == 0) {
      __threadfence();
      __hip_atomic_store(slots + bid * 16, epoch, __ATOMIC_RELEASE, __HIP_MEMORY_SCOPE_AGENT);
      while (__hip_atomic_load(go, __ATOMIC_ACQUIRE, __HIP_MEMORY_SCOPE_AGENT) < epoch)
        __builtin_amdgcn_s_sleep(1);
    }
    __syncthreads();
  }
}

// projection: out[m, tout] for one batch; K = 1536 = [dh 1024 | actx 512]
__device__ __forceinline__ void project(int tid, int b,
    const float* __restrict__ dhb, const float* __restrict__ axb,
    const float* __restrict__ proj_w, const float* __restrict__ proj_b,
    float* __restrict__ out, int tout) {
  const int wid = tid >> 6, l = tid & 63;
  f4 xp[6];
#pragma unroll
  for (int c = 0; c < 6; ++c) {
    const int kf = l + 64 * c;
    const float* p = (c < 4) ? dhb + kf * 4 : axb + (kf - 256) * 4;
    xp[c] = *(const f4*)p;
  }
#pragma unroll
  for (int mi = 0; mi < 5; ++mi) {
    const int m = wid * 5 + mi;
    const f4* wr = (const f4*)(proj_w + (size_t)m * 1536);
    float s = 0.f;
#pragma unroll
    for (int c = 0; c < 6; ++c) s = dot4(wr[l + 64 * c], xp[c], s);
    s = wave_sum(s);
    if (l == 0) out[(size_t)b * 16000 + m * 200 + tout] = s + proj_b[m];
  }
}

__global__ __launch_bounds__(TPB, 4) void decoder_persistent_kernel(
    const float* __restrict__ memory, const float* __restrict__ dec_inp,
    const int* __restrict__ mem_len,
    const float* __restrict__ pw1, const float* __restrict__ pw2,
    const float* __restrict__ a_wih, const float* __restrict__ a_whh, const float* __restrict__ a_b,
    const float* __restrict__ d_wih, const float* __restrict__ d_whh, const float* __restrict__ d_b,
    const float* __restrict__ proj_w, const float* __restrict__ proj_b,
    const float* __restrict__ query_w, const float* __restrict__ memory_w,
    const float* __restrict__ v_w, const float* __restrict__ conv_w, const float* __restrict__ ldw,
    float* __restrict__ out, float* __restrict__ wsf) {
  // LDS: per-block bf16 weights resident across all 200 steps + scratch union
  __shared__ __align__(16) unsigned short Wc_sh[16 * 2568];  // 82,176 B (swizzled rows, K=[actx|ah|dh])
  __shared__ __align__(16) unsigned short Wa_sh[16 * 1800];  // 57,600 B (swizzled rows, K=[dec|actx|ah])
  __shared__ __align__(16) float scr[4096];                  // 16,384 B scratch union

  unsigned* slots = (unsigned*)wsf;
  const int tid = threadIdx.x;
  const int bid = blockIdx.x;
  const int jbase = bid * 4;
  unsigned epoch = 0;

  unsigned short* xU    = (unsigned short*)(wsf + O_XU);
  unsigned short* decfr = (unsigned short*)(wsf + O_DECFR);
  unsigned short* ldwbf = (unsigned short*)(wsf + O_LDWBF);
  float* convwt = wsf + O_CONVWT;
  float* pmem   = wsf + O_PMEM;

  // ================= PROLOGUE =================
  // P0a: prenet -> decfr bf16 frag layout [tt][k8][b][e]
  {
    uint32_t d00, d01, d10, d11;
    tf2x32(0u, 42u, 0u, 0u, d00, d01);
    tf2x32(0u, 42u, 0u, 1u, d10, d11);
    const int s = tid >> 8, st = tid & 255;
    float* xin = scr + s * 336;
    float* h1  = scr + s * 336 + 80;
    for (int base = bid * 4; base < 3200; base += NB * 4) {
      const int task = base + s;
      const int tt = task >> 4, b = task & 15;
      if (st < 80) xin[st] = (tt == 0) ? 0.f : dec_inp[(size_t)b * 16000 + st * 200 + (tt - 1)];
      __syncthreads();
      float acc = 0.f;
      const float* w1r = pw1 + st * 80;
#pragma unroll 4
      for (int mm = 0; mm < 80; ++mm) acc = fmaf(xin[mm], w1r[mm], acc);
      acc = fmaxf(acc, 0.f);
      const uint32_t idx = (uint32_t)task * 256u + (uint32_t)st;
      acc = (tf_fold(d00, d01, idx) >> 31) ? 0.f : acc * 2.f;
      h1[st] = acc;
      __syncthreads();
      float acc2 = 0.f;
      const float* w2r = pw2 + st * 256;
#pragma unroll 4
      for (int pp = 0; pp < 256; ++pp) acc2 = fmaf(h1[pp], w2r[pp], acc2);
      acc2 = fmaxf(acc2, 0.f);
      acc2 = (tf_fold(d10, d11, idx) >> 31) ? 0.f : acc2 * 2.f;
      decfr[(size_t)tt * 4096 + (st >> 3) * 128 + b * 8 + (st & 7)] = f2bf(acc2);
      __syncthreads();
    }
  }
  // P0b: pmem = memory @ memory_w.T
  {
    const int s = tid >> 7, st = tid & 127;
    for (int base = bid * 8; base < 4096; base += NB * 8) {
      const int task = base + s;
      pmem[(size_t)task * 128 + st] =
          dot_f4(memory + (size_t)task * 512, memory_w + (size_t)st * 512, 128);
    }
  }
  // P0c: weights -> LDS bf16, swizzled. Rows n = jloc*4 + g <-> global row g*1024 + jbase + jloc.
  // Wc K-layout permuted to [actx(512) | ah(1024) | dh(1024)] to match unified xU.
  for (int n = 0; n < 16; ++n) {
    const int g = n & 3, jl = n >> 2;
    const int row = g * 1024 + jbase + jl;
    const float* wC1 = d_wih + (size_t)row * 1536;   // [ah 1024 | actx 512]
    const float* wC2 = d_whh + (size_t)row * 1024;   // dh
    for (int k = tid; k < 2560; k += TPB) {
      float v;
      if (k < 512)       v = wC1[1024 + k];          // actx
      else if (k < 1536) v = wC1[k - 512];           // ah
      else               v = wC2[k - 1536];          // dh
      Wc_sh[n * 2568 + SWZ(n, k)] = f2bf(v);
    }
    const float* wA1 = a_wih + (size_t)row * 768;    // [dec 256 | actx 512]
    const float* wA2 = a_whh + (size_t)row * 1024;   // ah
    for (int k = tid; k < 1792; k += TPB)
      Wa_sh[n * 1800 + SWZ(n, k)] = f2bf(k < 768 ? wA1[k] : wA2[k - 768]);
  }
  // P0d: small weight copies
  if (bid == 0) for (int i = tid; i < 4096; i += TPB) ldwbf[i] = f2bf(ldw[i]);
  if (bid == 1) for (int i = tid; i < 1984; i += TPB) {
    const int o = i & 31, ck = i >> 5;
    convwt[ck * 32 + o] = conv_w[o * 62 + ck];
  }
  ++epoch; grid_sync(slots, epoch, tid, bid);

  // ================= MAIN LOOP (t = -1 runs A(0) only) =================
  for (int t = -1; t < 200; ++t) {
    if (t >= 0) {
      // ---- P1P2: full attention for batch b (blocks 0..15) | proj t-1 (16..31) ----
      if (bid < 16) {
        const int b = bid;
        float* awst  = scr;              // [2][160]  window p=113..272
        float* q_s   = scr + 320;        // [128]
        float* e_red = scr + 448;        // [2][128]
        unsigned short* loc_s = (unsigned short*)(scr + 704);  // [128][40] bf16
        float* red8  = scr;              // [8]   (reuse; awst dead)
        float* awv_s = scr + 16;         // [128] (reuse)
        float* part  = scr + 144;        // [2][512] (reuse)
        if (tid < 320) {
          const int c2 = tid / 160, j = tid % 160, p = 113 + j;
          awst[c2 * 160 + j] = (p < 256) ? wsf[(c2 ? O_AWC : O_AW) + b * 256 + p] : 0.f;
        }
        __syncthreads();
        // conv: thread = (ttl 0..127, og 0..7 -> 4 filters)
        {
          const int ttl = tid >> 3, o0 = (tid & 7) * 4;
          float l0 = 0.f, l1 = 0.f, l2 = 0.f, l3 = 0.f;
#pragma unroll
          for (int c2 = 0; c2 < 2; ++c2) {
            const float* src = awst + c2 * 160 + ttl;        // src[k] = window[tt-15+k]
            const float* wp  = convwt + (c2 * 31) * 32 + o0;
#pragma unroll
            for (int k = 0; k < 31; ++k) {
              const float v = src[k];
              const f4 wv = *(const f4*)(wp + k * 32);
              l0 = fmaf(v, wv.x, l0); l1 = fmaf(v, wv.y, l1);
              l2 = fmaf(v, wv.z, l2); l3 = fmaf(v, wv.w, l3);
            }
          }
          unsigned short* lp = loc_s + ttl * 40 + o0;
          lp[0] = f2bf(l0); lp[1] = f2bf(l1); lp[2] = f2bf(l2); lp[3] = f2bf(l3);
        }
        // query: 16 waves x 8 rows = all 128 a-dims
        {
          const int w = tid >> 6, l = tid & 63;
          f4 xq[4];
#pragma unroll
          for (int c = 0; c < 4; ++c)
            xq[c] = *(const f4*)(wsf + O_AH + b * 1024 + (l + 64 * c) * 4);
#pragma unroll
          for (int i = 0; i < 8; ++i) {
            const int a = w * 8 + i;
            const f4* wr = (const f4*)(query_w + (size_t)a * 1024);
            float s = 0.f;
#pragma unroll
            for (int c = 0; c < 4; ++c) s = dot4(wr[l + 64 * c], xq[c], s);
            s = wave_sum(s);
            if (l == 0) q_s[a] = s;
          }
        }
        __syncthreads();
        // dense via MFMA: wave w -> ttile = w>>1, atiles (w&1)*4 + {0..3}
        {
          const int w = tid >> 6, l = tid & 63, q = l >> 4, c = l & 15;
          const int ttile = w >> 1;
          const short8 af = *(const short8*)(loc_s + (ttile * 16 + c) * 40 + q * 8);
          float eacc[4] = {0.f, 0.f, 0.f, 0.f};
#pragma unroll
          for (int at = 0; at < 4; ++at) {
            const int a = ((w & 1) * 4 + at) * 16 + c;
            const short8 bf = *(const short8*)(ldwbf + a * 32 + q * 8);
            f32x4 d = {0.f, 0.f, 0.f, 0.f};
            d = __builtin_amdgcn_mfma_f32_16x16x32_bf16(af, bf, d, 0, 0, 0);
            const float qa = q_s[a];
            const float vv = v_w[a];
#pragma unroll
            for (int r = 0; r < 4; ++r) {
              const int tt = 128 + ttile * 16 + 4 * q + r;
              float s = d[r] + qa + pmem[(size_t)(b * 256 + tt) * 128 + a];
              s = fminf(20.f, fmaxf(-20.f, s));
              eacc[r] = fmaf(tanhf(s), vv, eacc[r]);
            }
          }
#pragma unroll
          for (int r = 0; r < 4; ++r) {
            float e = eacc[r];
            e += __shfl_xor(e, 1, 64); e += __shfl_xor(e, 2, 64);
            e += __shfl_xor(e, 4, 64); e += __shfl_xor(e, 8, 64);
            if (c == 0) e_red[(w & 1) * 128 + ttile * 16 + 4 * q + r] = e;
          }
        }
        __syncthreads();
        // softmax over tt (mask: tt < len -> -inf) — in-block
        const int lenb = mem_len[b];
        float e = 0.f, p = 0.f; bool live = false;
        if (tid < 128) {
          const int tt = 128 + tid;
          live = tt >= lenb;
          e = e_red[tid] + e_red[128 + tid];
          float m = live ? e : -3.4e38f;
          m = wave_max(m);
          if ((tid & 63) == 0) red8[tid >> 6] = m;
        }
        __syncthreads();
        const float mx = fmaxf(red8[0], red8[1]);
        if (tid < 128) {
          p = live ? expf(e - mx) : 0.f;
          float z = wave_sum(p);
          if ((tid & 63) == 0) red8[2 + (tid >> 6)] = z;
        }
        __syncthreads();
        if (tid < 128) {
          const float z = red8[2] + red8[3];
          const float awv = live ? p / z : 0.f;
          awv_s[tid] = awv;
          wsf[O_AW + b * 256 + 128 + tid] = awv;
          if (live) wsf[O_AWC + b * 256 + 128 + tid] += awv;
        }
        __syncthreads();
        // actx = aw @ memory
        {
          const int th = tid >> 9, e0 = tid & 511;
          float a = 0.f;
#pragma unroll 4
          for (int j = 0; j < 64; ++j) {
            const int tt = 128 + th * 64 + j;
            a = fmaf(awv_s[th * 64 + j], memory[((size_t)(b * 256 + tt)) * 512 + e0], a);
          }
          part[th * 512 + e0] = a;
        }
        __syncthreads();
        if (tid < 512) {
          const float a = part[tid] + part[512 + tid];
          wsf[O_ACTX + (t & 1) * 8192 + b * 512 + tid] = a;
          xU[(t & 1) * XU_PAR + (tid >> 3) * 128 + b * 8 + (tid & 7)] = f2bf(a);  // actx k8 0..63
        }
      } else if (bid < 32 && t > 0) {
        const int b = bid - 16;
        project(tid, b, wsf + O_DH + b * 1024,
                wsf + O_ACTX + ((t - 1) & 1) * 8192 + b * 512, proj_w, proj_b, out, t - 1);
      }
      ++epoch; grid_sync(slots, epoch, tid, bid);
    }

    // ---- P3: C(t) MFMA (waves 0..7) + A(t+1) MFMA (waves 8..15) + pointwise ----
    {
      const int rp = t & 1;            // read parity  (t = -1 -> 1, zeros)
      const unsigned short* xUr = xU + rp * XU_PAR;
      unsigned short* xUw = xU + (rp ^ 1) * XU_PAR;
      float* redC = scr;          // [8][256]
      float* redA = scr + 2048;   // [8][256]
      const int w = tid >> 6, l = tid & 63;
      const int q = l >> 4, c = l & 15;
      if (w < 8) {
        if (t >= 0) {
          f32x4 acc = {0.f, 0.f, 0.f, 0.f};
#pragma unroll
          for (int i = 0; i < 10; ++i) {
            const int k32 = w * 10 + i;                          // 0..79 = [actx|ah|dh]
            const short8 af = *(const short8*)(xUr + k32 * 512 + l * 8);
            const short8 bf = *(const short8*)(Wc_sh + c * 2568 + SWZ(c, q * 8 + k32 * 32));
            acc = __builtin_amdgcn_mfma_f32_16x16x32_bf16(af, bf, acc, 0, 0, 0);
          }
#pragma unroll
          for (int r = 0; r < 4; ++r) redC[w * 256 + (4 * q + r) * 16 + c] = acc[r];
        }
      } else {
        if (t < 199) {
          const unsigned short* dfr = decfr + (size_t)(t + 1) * 4096;
          f32x4 acc = {0.f, 0.f, 0.f, 0.f};
#pragma unroll
          for (int i = 0; i < 7; ++i) {
            const int k32 = (w - 8) * 7 + i;                     // 0..55 = [dec|actx|ah]
            const unsigned short* src = (k32 < 8) ? (dfr + k32 * 512) : (xUr + (k32 - 8) * 512);
            const short8 af = *(const short8*)(src + l * 8);
            const short8 bf = *(const short8*)(Wa_sh + c * 1800 + SWZ(c, q * 8 + k32 * 32));
            acc = __builtin_amdgcn_mfma_f32_16x16x32_bf16(af, bf, acc, 0, 0, 0);
          }
#pragma unroll
          for (int r = 0; r < 4; ++r) redA[(w - 8) * 256 + (4 * q + r) * 16 + c] = acc[r];
        }
      }
      __syncthreads();
      if (tid < 64) {
        if (t >= 0) {            // C pointwise -> dh(t)
          const int b = tid >> 2, jl = tid & 3, J = jbase + jl;
          float gv[4];
#pragma unroll
          for (int g = 0; g < 4; ++g) {
            float s = d_b[g * 1024 + J];
#pragma unroll
            for (int w2 = 0; w2 < 8; ++w2) s += redC[w2 * 256 + b * 16 + (jl * 4 + g)];
            gv[g] = s;
          }
          const int bi = b * 1024 + J;
          const float c2v = sigm(gv[1]) * wsf[O_DC + bi] + sigm(gv[0]) * tanhf(gv[2]);
          wsf[O_DC + bi] = c2v;
          const float h = sigm(gv[3]) * tanhf(c2v);
          wsf[O_DH + bi] = h;
          xUw[(192 + (J >> 3)) * 128 + b * 8 + (J & 7)] = f2bf(h);   // dh k8 192..319
        }
      } else if (tid < 128) {
        if (t < 199) {           // A(t+1) pointwise -> ah(t+1)
          const int t2 = tid - 64;
          const int b = t2 >> 2, jl = t2 & 3, J = jbase + jl;
          float gv[4];
#pragma unroll
          for (int g = 0; g < 4; ++g) {
            float s = a_b[g * 1024 + J];
#pragma unroll
            for (int w2 = 0; w2 < 8; ++w2) s += redA[w2 * 256 + b * 16 + (jl * 4 + g)];
            gv[g] = s;
          }
          const int bi = b * 1024 + J;
          const float c2v = sigm(gv[1]) * wsf[O_AC + bi] + sigm(gv[0]) * tanhf(gv[2]);
          wsf[O_AC + bi] = c2v;
          const float h = sigm(gv[3]) * tanhf(c2v);
          wsf[O_AH + bi] = h;
          xUw[(64 + (J >> 3)) * 128 + b * 8 + (J & 7)] = f2bf(h);    // ah k8 64..191
        }
      }
    }
    ++epoch; grid_sync(slots, epoch, tid, bid);
  }

  // ---- final projection t = 199 (actx parity 1) ----
  if (bid >= 16 && bid < 32) {
    const int b = bid - 16;
    project(tid, b, wsf + O_DH + b * 1024, wsf + O_ACTX + 8192 + b * 512,
            proj_w, proj_b, out, 199);
  }
}

extern "C" void kernel_launch(void* const* d_in, const int* in_sizes, int n_in,
                              void* d_out, int out_size, void* d_ws, size_t ws_size,
                              hipStream_t stream) {
  (void)in_sizes; (void)n_in; (void)out_size; (void)ws_size;
  const float* memory   = (const float*)d_in[0];
  const float* dec_inp  = (const float*)d_in[1];
  const int*   mem_len  = (const int*)d_in[2];
  const float* pw1      = (const float*)d_in[3];
  const float* pw2      = (const float*)d_in[4];
  const float* a_wih    = (const float*)d_in[5];
  const float* a_whh    = (const float*)d_in[6];
  const float* a_b      = (const float*)d_in[7];
  const float* d_wih    = (const float*)d_in[8];
  const float* d_whh    = (const float*)d_in[9];
  const float* d_b      = (const float*)d_in[10];
  const float* proj_w   = (const float*)d_in[11];
  const float* proj_b   = (const float*)d_in[12];
  const float* query_w  = (const float*)d_in[13];
  const float* memory_w = (const float*)d_in[14];
  const float* v_w      = (const float*)d_in[15];
  const float* conv_w   = (const float*)d_in[16];
  const float* ldw      = (const float*)d_in[17];

  hipMemsetAsync(d_ws, 0, ZERO_BYTES, stream);
  decoder_persistent_kernel<<<NB, TPB, 0, stream>>>(
      memory, dec_inp, mem_len, pw1, pw2, a_wih, a_whh, a_b,
      d_wih, d_whh, d_b, proj_w, proj_b, query_w, memory_w, v_w, conv_w, ldw,
      (float*)d_out, (float*)d_ws);
}

// Round 9
// 16018.127 us; speedup vs baseline: 4.1845x; 4.1845x over previous
//
#include <hip/hip_runtime.h>
#include <cstdint>
#include <cstddef>

#define TPB 1024
#define NB  256

typedef float4 f4;
typedef float f32x4 __attribute__((ext_vector_type(4)));
typedef short short8 __attribute__((ext_vector_type(8)));
typedef unsigned long long u64;

// ---------------- ws float offsets ----------------
#define O_SLOT   0         // uint slots[256][16] + go flag
#define O_AH     4352      // f32 [16][1024]
#define O_AC     20736
#define O_DH     37120
#define O_DC     53504
#define O_ACTX   69888     // f32 [2][16][512]
#define O_AW     86272     // f32 [16][256]
#define O_AWC    90368
#define O_XU     94464     // bf16 [2][320 k8][16 b][8 e]  (actx 0..63 | ah 64..191 | dh 192..319)
#define O_DECFR  135424    // bf16 [200][32][16][8]
#define O_PMEM   545024    // f32 [4096][128]
#define O_LDWBF  1069312   // bf16 [128][32]
#define O_CONVWT 1071360   // f32 [62][32]
#define ZERO_BYTES (O_DECFR * 4)

#define XU_PAR  40960      // shorts per parity copy

// LDS weight-row swizzle: 16B-granular XOR, bijective (row lengths % 64 == 0)
#define SWZ(n, k) ((k) ^ (((n) & 7) << 3))

// ---------------- JAX Threefry-2x32 (partitionable) ----------------
__device__ __forceinline__ void tf2x32(uint32_t k0, uint32_t k1, uint32_t x0, uint32_t x1,
                                       uint32_t& o0, uint32_t& o1) {
  uint32_t ks2 = k0 ^ k1 ^ 0x1BD11BDAu;
  x0 += k0; x1 += k1;
#define TFR(r) { x0 += x1; x1 = (x1 << (r)) | (x1 >> (32 - (r))); x1 ^= x0; }
  TFR(13) TFR(15) TFR(26) TFR(6)
  x0 += k1;  x1 += ks2 + 1u;
  TFR(17) TFR(29) TFR(16) TFR(24)
  x0 += ks2; x1 += k0 + 2u;
  TFR(13) TFR(15) TFR(26) TFR(6)
  x0 += k0;  x1 += k1 + 3u;
  TFR(17) TFR(29) TFR(16) TFR(24)
  x0 += k1;  x1 += ks2 + 4u;
  TFR(13) TFR(15) TFR(26) TFR(6)
  x0 += ks2; x1 += k0 + 5u;
#undef TFR
  o0 = x0; o1 = x1;
}
__device__ __forceinline__ uint32_t tf_fold(uint32_t k0, uint32_t k1, uint32_t idx) {
  uint32_t a, b; tf2x32(k0, k1, 0u, idx, a, b); return a ^ b;
}

// ---------------- helpers ----------------
__device__ __forceinline__ unsigned short f2bf(float x) {
  uint32_t u = __float_as_uint(x);
  u += 0x7fffu + ((u >> 16) & 1u);
  return (unsigned short)(u >> 16);
}
__device__ __forceinline__ float dot4(f4 a, f4 b, float acc) {
  acc = fmaf(a.x, b.x, acc); acc = fmaf(a.y, b.y, acc);
  acc = fmaf(a.z, b.z, acc); acc = fmaf(a.w, b.w, acc);
  return acc;
}
__device__ __forceinline__ float dot_f4(const float* __restrict__ x, const float* __restrict__ w, int n4) {
  const f4* xv = (const f4*)x; const f4* wv = (const f4*)w;
  float s = 0.f;
#pragma unroll 8
  for (int k = 0; k < n4; ++k) s = dot4(xv[k], wv[k], s);
  return s;
}
__device__ __forceinline__ float sigm(float x) { return 1.f / (1.f + expf(-x)); }
__device__ __forceinline__ float wave_sum(float s) {
#pragma unroll
  for (int off = 32; off; off >>= 1) s += __shfl_xor(s, off, 64);
  return s;
}
__device__ __forceinline__ float wave_max(float s) {
#pragma unroll
  for (int off = 32; off; off >>= 1) s = fmaxf(s, __shfl_xor(s, off, 64));
  return s;
}

// sc-bit (agent-scope, cache-bypassing, NON-invalidating) loads for cross-block state
__device__ __forceinline__ f4 load_sc_f4(const float* p) {
  union { f4 v; u64 u[2]; } r;
  r.u[0] = __hip_atomic_load((const u64*)p,     __ATOMIC_RELAXED, __HIP_MEMORY_SCOPE_AGENT);
  r.u[1] = __hip_atomic_load((const u64*)p + 1, __ATOMIC_RELAXED, __HIP_MEMORY_SCOPE_AGENT);
  return r.v;
}
__device__ __forceinline__ short8 load_sc_s8(const unsigned short* p) {
  union { short8 v; u64 u[2]; } r;
  r.u[0] = __hip_atomic_load((const u64*)p,     __ATOMIC_RELAXED, __HIP_MEMORY_SCOPE_AGENT);
  r.u[1] = __hip_atomic_load((const u64*)p + 1, __ATOMIC_RELAXED, __HIP_MEMORY_SCOPE_AGENT);
  return r.v;
}

// Poll with RELAXED loads (no buffer_inv). Rare acquire hedge in case relaxed
// visibility ever stalls (bounds staleness; never triggers in the good case).
__device__ __forceinline__ void poll_ge(unsigned* p, unsigned epoch) {
  int spins = 0;
  while (__hip_atomic_load(p, __ATOMIC_RELAXED, __HIP_MEMORY_SCOPE_AGENT) < epoch) {
    __builtin_amdgcn_s_sleep(1);
    if (++spins >= (1 << 14)) {
      spins = 0;
      (void)__hip_atomic_load(p, __ATOMIC_ACQUIRE, __HIP_MEMORY_SCOPE_AGENT);
    }
  }
}

// Distributed grid barrier: release fence = wbl2 (writeback only, L2 kept warm),
// relaxed sc-stores/loads for slots/go. No L2 invalidation in steady state.
__device__ __forceinline__ void grid_sync(unsigned* slots, unsigned epoch, int tid, int bid) {
  unsigned* go = slots + NB * 16;
  __syncthreads();                                         // waitcnt: block's stores in L2
  if (tid == 0) __builtin_amdgcn_fence(__ATOMIC_RELEASE, "agent");   // wbl2 -> LLC
  if (bid == 0) {
    if (tid < NB) {
      if (tid == 0)
        __hip_atomic_store(slots, epoch, __ATOMIC_RELAXED, __HIP_MEMORY_SCOPE_AGENT);
      poll_ge(slots + tid * 16, epoch);
    }
    __syncthreads();
    if (tid == 0)
      __hip_atomic_store(go, epoch, __ATOMIC_RELAXED, __HIP_MEMORY_SCOPE_AGENT);
  } else {
    if (tid == 0) {
      __hip_atomic_store(slots + bid * 16, epoch, __ATOMIC_RELAXED, __HIP_MEMORY_SCOPE_AGENT);
      poll_ge(go, epoch);
    }
    __syncthreads();
  }
}

// projection: out[m, tout] for one batch; K = 1536 = [dh 1024 | actx 512] (cross-block -> sc loads)
__device__ __forceinline__ void project(int tid, int b,
    const float* __restrict__ dhb, const float* __restrict__ axb,
    const float* __restrict__ proj_w, const float* __restrict__ proj_b,
    float* __restrict__ out, int tout) {
  const int wid = tid >> 6, l = tid & 63;
  f4 xp[6];
#pragma unroll
  for (int c = 0; c < 6; ++c) {
    const int kf = l + 64 * c;
    const float* p = (c < 4) ? dhb + kf * 4 : axb + (kf - 256) * 4;
    xp[c] = load_sc_f4(p);
  }
#pragma unroll
  for (int mi = 0; mi < 5; ++mi) {
    const int m = wid * 5 + mi;
    const f4* wr = (const f4*)(proj_w + (size_t)m * 1536);
    float s = 0.f;
#pragma unroll
    for (int c = 0; c < 6; ++c) s = dot4(wr[l + 64 * c], xp[c], s);
    s = wave_sum(s);
    if (l == 0) out[(size_t)b * 16000 + m * 200 + tout] = s + proj_b[m];
  }
}

__global__ __launch_bounds__(TPB, 4) void decoder_persistent_kernel(
    const float* __restrict__ memory, const float* __restrict__ dec_inp,
    const int* __restrict__ mem_len,
    const float* __restrict__ pw1, const float* __restrict__ pw2,
    const float* __restrict__ a_wih, const float* __restrict__ a_whh, const float* __restrict__ a_b,
    const float* __restrict__ d_wih, const float* __restrict__ d_whh, const float* __restrict__ d_b,
    const float* __restrict__ proj_w, const float* __restrict__ proj_b,
    const float* __restrict__ query_w, const float* __restrict__ memory_w,
    const float* __restrict__ v_w, const float* __restrict__ conv_w, const float* __restrict__ ldw,
    float* __restrict__ out, float* __restrict__ wsf) {
  __shared__ __align__(16) unsigned short Wc_sh[16 * 2568];  // 82,176 B (swizzled rows, K=[actx|ah|dh])
  __shared__ __align__(16) unsigned short Wa_sh[16 * 1800];  // 57,600 B (swizzled rows, K=[dec|actx|ah])
  __shared__ __align__(16) float scr[4096];                  // 16,384 B scratch union

  unsigned* slots = (unsigned*)wsf;
  const int tid = threadIdx.x;
  const int bid = blockIdx.x;
  const int jbase = bid * 4;
  unsigned epoch = 0;

  unsigned short* xU    = (unsigned short*)(wsf + O_XU);
  unsigned short* decfr = (unsigned short*)(wsf + O_DECFR);
  unsigned short* ldwbf = (unsigned short*)(wsf + O_LDWBF);
  float* convwt = wsf + O_CONVWT;
  float* pmem   = wsf + O_PMEM;

  // ================= PROLOGUE =================
  // P0a: prenet -> decfr bf16 frag layout [tt][k8][b][e]
  {
    uint32_t d00, d01, d10, d11;
    tf2x32(0u, 42u, 0u, 0u, d00, d01);
    tf2x32(0u, 42u, 0u, 1u, d10, d11);
    const int s = tid >> 8, st = tid & 255;
    float* xin = scr + s * 336;
    float* h1  = scr + s * 336 + 80;
    for (int base = bid * 4; base < 3200; base += NB * 4) {
      const int task = base + s;
      const int tt = task >> 4, b = task & 15;
      if (st < 80) xin[st] = (tt == 0) ? 0.f : dec_inp[(size_t)b * 16000 + st * 200 + (tt - 1)];
      __syncthreads();
      float acc = 0.f;
      const float* w1r = pw1 + st * 80;
#pragma unroll 4
      for (int mm = 0; mm < 80; ++mm) acc = fmaf(xin[mm], w1r[mm], acc);
      acc = fmaxf(acc, 0.f);
      const uint32_t idx = (uint32_t)task * 256u + (uint32_t)st;
      acc = (tf_fold(d00, d01, idx) >> 31) ? 0.f : acc * 2.f;
      h1[st] = acc;
      __syncthreads();
      float acc2 = 0.f;
      const float* w2r = pw2 + st * 256;
#pragma unroll 4
      for (int pp = 0; pp < 256; ++pp) acc2 = fmaf(h1[pp], w2r[pp], acc2);
      acc2 = fmaxf(acc2, 0.f);
      acc2 = (tf_fold(d10, d11, idx) >> 31) ? 0.f : acc2 * 2.f;
      decfr[(size_t)tt * 4096 + (st >> 3) * 128 + b * 8 + (st & 7)] = f2bf(acc2);
      __syncthreads();
    }
  }
  // P0b: pmem = memory @ memory_w.T
  {
    const int s = tid >> 7, st = tid & 127;
    for (int base = bid * 8; base < 4096; base += NB * 8) {
      const int task = base + s;
      pmem[(size_t)task * 128 + st] =
          dot_f4(memory + (size_t)task * 512, memory_w + (size_t)st * 512, 128);
    }
  }
  // P0c: weights -> LDS bf16, swizzled. Wc K-layout = [actx(512) | ah(1024) | dh(1024)].
  for (int n = 0; n < 16; ++n) {
    const int g = n & 3, jl = n >> 2;
    const int row = g * 1024 + jbase + jl;
    const float* wC1 = d_wih + (size_t)row * 1536;   // [ah 1024 | actx 512]
    const float* wC2 = d_whh + (size_t)row * 1024;   // dh
    for (int k = tid; k < 2560; k += TPB) {
      float v;
      if (k < 512)       v = wC1[1024 + k];          // actx
      else if (k < 1536) v = wC1[k - 512];           // ah
      else               v = wC2[k - 1536];          // dh
      Wc_sh[n * 2568 + SWZ(n, k)] = f2bf(v);
    }
    const float* wA1 = a_wih + (size_t)row * 768;    // [dec 256 | actx 512]
    const float* wA2 = a_whh + (size_t)row * 1024;   // ah
    for (int k = tid; k < 1792; k += TPB)
      Wa_sh[n * 1800 + SWZ(n, k)] = f2bf(k < 768 ? wA1[k] : wA2[k - 768]);
  }
  // P0d: small weight copies
  if (bid == 0) for (int i = tid; i < 4096; i += TPB) ldwbf[i] = f2bf(ldw[i]);
  if (bid == 1) for (int i = tid; i < 1984; i += TPB) {
    const int o = i & 31, ck = i >> 5;
    convwt[ck * 32 + o] = conv_w[o * 62 + ck];
  }
  ++epoch; grid_sync(slots, epoch, tid, bid);

  // ================= MAIN LOOP (t = -1 runs A(0) only) =================
  for (int t = -1; t < 200; ++t) {
    if (t >= 0) {
      // ---- P1P2: full attention (blocks 0..15) | proj t-1 (16..31) ----
      if (bid < 16) {
        const int b = bid;
        float* awst  = scr;              // [2][160]
        float* q_s   = scr + 320;        // [128]
        float* e_red = scr + 448;        // [2][128]
        unsigned short* loc_s = (unsigned short*)(scr + 704);  // [128][40] bf16
        float* red8  = scr;              // reuse
        float* awv_s = scr + 16;
        float* part  = scr + 144;
        if (tid < 320) {
          const int c2 = tid / 160, j = tid % 160, p = 113 + j;
          awst[c2 * 160 + j] = (p < 256) ? wsf[(c2 ? O_AWC : O_AW) + b * 256 + p] : 0.f;
        }
        __syncthreads();
        // conv
        {
          const int ttl = tid >> 3, o0 = (tid & 7) * 4;
          float l0 = 0.f, l1 = 0.f, l2 = 0.f, l3 = 0.f;
#pragma unroll
          for (int c2 = 0; c2 < 2; ++c2) {
            const float* src = awst + c2 * 160 + ttl;
            const float* wp  = convwt + (c2 * 31) * 32 + o0;
#pragma unroll
            for (int k = 0; k < 31; ++k) {
              const float v = src[k];
              const f4 wv = *(const f4*)(wp + k * 32);
              l0 = fmaf(v, wv.x, l0); l1 = fmaf(v, wv.y, l1);
              l2 = fmaf(v, wv.z, l2); l3 = fmaf(v, wv.w, l3);
            }
          }
          unsigned short* lp = loc_s + ttl * 40 + o0;
          lp[0] = f2bf(l0); lp[1] = f2bf(l1); lp[2] = f2bf(l2); lp[3] = f2bf(l3);
        }
        // query: ah is cross-block -> sc loads; query_w plain (L2-resident now)
        {
          const int w = tid >> 6, l = tid & 63;
          f4 xq[4];
#pragma unroll
          for (int c = 0; c < 4; ++c)
            xq[c] = load_sc_f4(wsf + O_AH + b * 1024 + (l + 64 * c) * 4);
#pragma unroll
          for (int i = 0; i < 8; ++i) {
            const int a = w * 8 + i;
            const f4* wr = (const f4*)(query_w + (size_t)a * 1024);
            float s = 0.f;
#pragma unroll
            for (int c = 0; c < 4; ++c) s = dot4(wr[l + 64 * c], xq[c], s);
            s = wave_sum(s);
            if (l == 0) q_s[a] = s;
          }
        }
        __syncthreads();
        // dense via MFMA
        {
          const int w = tid >> 6, l = tid & 63, q = l >> 4, c = l & 15;
          const int ttile = w >> 1;
          const short8 af = *(const short8*)(loc_s + (ttile * 16 + c) * 40 + q * 8);
          float eacc[4] = {0.f, 0.f, 0.f, 0.f};
#pragma unroll
          for (int at = 0; at < 4; ++at) {
            const int a = ((w & 1) * 4 + at) * 16 + c;
            const short8 bf = *(const short8*)(ldwbf + a * 32 + q * 8);
            f32x4 d = {0.f, 0.f, 0.f, 0.f};
            d = __builtin_amdgcn_mfma_f32_16x16x32_bf16(af, bf, d, 0, 0, 0);
            const float qa = q_s[a];
            const float vv = v_w[a];
#pragma unroll
            for (int r = 0; r < 4; ++r) {
              const int tt = 128 + ttile * 16 + 4 * q + r;
              float s = d[r] + qa + pmem[(size_t)(b * 256 + tt) * 128 + a];
              s = fminf(20.f, fmaxf(-20.f, s));
              eacc[r] = fmaf(tanhf(s), vv, eacc[r]);
            }
          }
#pragma unroll
          for (int r = 0; r < 4; ++r) {
            float e = eacc[r];
            e += __shfl_xor(e, 1, 64); e += __shfl_xor(e, 2, 64);
            e += __shfl_xor(e, 4, 64); e += __shfl_xor(e, 8, 64);
            if (c == 0) e_red[(w & 1) * 128 + ttile * 16 + 4 * q + r] = e;
          }
        }
        __syncthreads();
        // softmax (mask: tt < len -> -inf)
        const int lenb = mem_len[b];
        float e = 0.f, p = 0.f; bool live = false;
        if (tid < 128) {
          const int tt = 128 + tid;
          live = tt >= lenb;
          e = e_red[tid] + e_red[128 + tid];
          float m = live ? e : -3.4e38f;
          m = wave_max(m);
          if ((tid & 63) == 0) red8[tid >> 6] = m;
        }
        __syncthreads();
        const float mx = fmaxf(red8[0], red8[1]);
        if (tid < 128) {
          p = live ? expf(e - mx) : 0.f;
          float z = wave_sum(p);
          if ((tid & 63) == 0) red8[2 + (tid >> 6)] = z;
        }
        __syncthreads();
        if (tid < 128) {
          const float z = red8[2] + red8[3];
          const float awv = live ? p / z : 0.f;
          awv_s[tid] = awv;
          wsf[O_AW + b * 256 + 128 + tid] = awv;
          if (live) wsf[O_AWC + b * 256 + 128 + tid] += awv;
        }
        __syncthreads();
        // actx = aw @ memory (memory read-only, L2-resident now)
        {
          const int th = tid >> 9, e0 = tid & 511;
          float a = 0.f;
#pragma unroll 4
          for (int j = 0; j < 64; ++j) {
            const int tt = 128 + th * 64 + j;
            a = fmaf(awv_s[th * 64 + j], memory[((size_t)(b * 256 + tt)) * 512 + e0], a);
          }
          part[th * 512 + e0] = a;
        }
        __syncthreads();
        if (tid < 512) {
          const float a = part[tid] + part[512 + tid];
          wsf[O_ACTX + (t & 1) * 8192 + b * 512 + tid] = a;
          xU[(t & 1) * XU_PAR + (tid >> 3) * 128 + b * 8 + (tid & 7)] = f2bf(a);
        }
      } else if (bid < 32 && t > 0) {
        const int b = bid - 16;
        project(tid, b, wsf + O_DH + b * 1024,
                wsf + O_ACTX + ((t - 1) & 1) * 8192 + b * 512, proj_w, proj_b, out, t - 1);
      }
      ++epoch; grid_sync(slots, epoch, tid, bid);
    }

    // ---- P3: C(t) MFMA (waves 0..7) + A(t+1) MFMA (waves 8..15) + pointwise ----
    {
      const int rp = t & 1;
      const unsigned short* xUr = xU + rp * XU_PAR;
      unsigned short* xUw = xU + (rp ^ 1) * XU_PAR;
      float* redC = scr;          // [8][256]
      float* redA = scr + 2048;   // [8][256]
      const int w = tid >> 6, l = tid & 63;
      const int q = l >> 4, c = l & 15;
      if (w < 8) {
        if (t >= 0) {
          f32x4 acc = {0.f, 0.f, 0.f, 0.f};
#pragma unroll
          for (int i = 0; i < 10; ++i) {
            const int k32 = w * 10 + i;                        // [actx|ah|dh]
            const short8 af = load_sc_s8(xUr + k32 * 512 + l * 8);
            const short8 bf = *(const short8*)(Wc_sh + c * 2568 + SWZ(c, q * 8 + k32 * 32));
            acc = __builtin_amdgcn_mfma_f32_16x16x32_bf16(af, bf, acc, 0, 0, 0);
          }
#pragma unroll
          for (int r = 0; r < 4; ++r) redC[w * 256 + (4 * q + r) * 16 + c] = acc[r];
        }
      } else {
        if (t < 199) {
          const unsigned short* dfr = decfr + (size_t)(t + 1) * 4096;
          f32x4 acc = {0.f, 0.f, 0.f, 0.f};
#pragma unroll
          for (int i = 0; i < 7; ++i) {
            const int k32 = (w - 8) * 7 + i;                   // [dec|actx|ah]
            short8 af;
            if (k32 < 8) af = *(const short8*)(dfr + k32 * 512 + l * 8);       // read-only, cached
            else         af = load_sc_s8(xUr + (k32 - 8) * 512 + l * 8);       // cross-block state
            const short8 bf = *(const short8*)(Wa_sh + c * 1800 + SWZ(c, q * 8 + k32 * 32));
            acc = __builtin_amdgcn_mfma_f32_16x16x32_bf16(af, bf, acc, 0, 0, 0);
          }
#pragma unroll
          for (int r = 0; r < 4; ++r) redA[(w - 8) * 256 + (4 * q + r) * 16 + c] = acc[r];
        }
      }
      __syncthreads();
      if (tid < 64) {
        if (t >= 0) {            // C pointwise -> dh(t)
          const int b = tid >> 2, jl = tid & 3, J = jbase + jl;
          float gv[4];
#pragma unroll
          for (int g = 0; g < 4; ++g) {
            float s = d_b[g * 1024 + J];
#pragma unroll
            for (int w2 = 0; w2 < 8; ++w2) s += redC[w2 * 256 + b * 16 + (jl * 4 + g)];
            gv[g] = s;
          }
          const int bi = b * 1024 + J;
          const float c2v = sigm(gv[1]) * wsf[O_DC + bi] + sigm(gv[0]) * tanhf(gv[2]);
          wsf[O_DC + bi] = c2v;
          const float h = sigm(gv[3]) * tanhf(c2v);
          wsf[O_DH + bi] = h;
          xUw[(192 + (J >> 3)) * 128 + b * 8 + (J & 7)] = f2bf(h);
        }
      } else if (tid < 128) {
        if (t < 199) {           // A(t+1) pointwise -> ah(t+1)
          const int t2 = tid - 64;
          const int b = t2 >> 2, jl = t2 & 3, J = jbase + jl;
          float gv[4];
#pragma unroll
          for (int g = 0; g < 4; ++g) {
            float s = a_b[g * 1024 + J];
#pragma unroll
            for (int w2 = 0; w2 < 8; ++w2) s += redA[w2 * 256 + b * 16 + (jl * 4 + g)];
            gv[g] = s;
          }
          const int bi = b * 1024 + J;
          const float c2v = sigm(gv[1]) * wsf[O_AC + bi] + sigm(gv[0]) * tanhf(gv[2]);
          wsf[O_AC + bi] = c2v;
          const float h = sigm(gv[3]) * tanhf(c2v);
          wsf[O_AH + bi] = h;
          xUw[(64 + (J >> 3)) * 128 + b * 8 + (J & 7)] = f2bf(h);
        }
      }
    }
    ++epoch; grid_sync(slots, epoch, tid, bid);
  }

  // ---- final projection t = 199 (actx parity 1) ----
  if (bid >= 16 && bid < 32) {
    const int b = bid - 16;
    project(tid, b, wsf + O_DH + b * 1024, wsf + O_ACTX + 8192 + b * 512,
            proj_w, proj_b, out, 199);
  }
}

extern "C" void kernel_launch(void* const* d_in, const int* in_sizes, int n_in,
                              void* d_out, int out_size, void* d_ws, size_t ws_size,
                              hipStream_t stream) {
  (void)in_sizes; (void)n_in; (void)out_size; (void)ws_size;
  const float* memory   = (const float*)d_in[0];
  const float* dec_inp  = (const float*)d_in[1];
  const int*   mem_len  = (const int*)d_in[2];
  const float* pw1      = (const float*)d_in[3];
  const float* pw2      = (const float*)d_in[4];
  const float* a_wih    = (const float*)d_in[5];
  const float* a_whh    = (const float*)d_in[6];
  const float* a_b      = (const float*)d_in[7];
  const float* d_wih    = (const float*)d_in[8];
  const float* d_whh    = (const float*)d_in[9];
  const float* d_b      = (const float*)d_in[10];
  const float* proj_w   = (const float*)d_in[11];
  const float* proj_b   = (const float*)d_in[12];
  const float* query_w  = (const float*)d_in[13];
  const float* memory_w = (const float*)d_in[14];
  const float* v_w      = (const float*)d_in[15];
  const float* conv_w   = (const float*)d_in[16];
  const float* ldw      = (const float*)d_in[17];

  hipMemsetAsync(d_ws, 0, ZERO_BYTES, stream);
  decoder_persistent_kernel<<<NB, TPB, 0, stream>>>(
      memory, dec_inp, mem_len, pw1, pw2, a_wih, a_whh, a_b,
      d_wih, d_whh, d_b, proj_w, proj_b, query_w, memory_w, v_w, conv_w, ldw,
      (float*)d_out, (float*)d_ws);
}

// Round 10
// 14363.892 us; speedup vs baseline: 4.6664x; 1.1152x over previous
//
#include <hip/hip_runtime.h>
#include <cstdint>
#include <cstddef>

#define TPB 1024
#define NB  256

typedef float4 f4;
typedef float f32x4 __attribute__((ext_vector_type(4)));
typedef short short8 __attribute__((ext_vector_type(8)));
typedef unsigned long long u64;

// ---------------- ws float offsets ----------------
#define O_SLOTB  0         // slotsB[256][16] uints; go at [4096]
#define O_SLOTA  4112      // slotsA[32][16] uints (partial barrier)
#define O_AH     4864      // f32 [16][1024]
#define O_AC     21248
#define O_DH     37632
#define O_DC     54016
#define O_ACTX   70400     // f32 [2][16][512]
#define O_AW     86784     // f32 [16][256]
#define O_AWC    90880
#define O_XU     94976     // bf16 [2][320 k8][16 b][8 e]  (actx 0..63 | ah 64..191 | dh 192..319)
#define O_DECFR  135936    // bf16 [200][32][16][8]
#define O_PMEM   545536    // f32 [4096][128]
#define O_LDWBF  1069824   // bf16 [128][32]
#define O_CONVWT 1071872   // f32 [62][32]
#define ZERO_BYTES (O_DECFR * 4)

#define XU_PAR  40960      // shorts per parity copy

// LDS weight-row swizzle: 16B-granular XOR, bijective (row lengths % 64 == 0)
#define SWZ(n, k) ((k) ^ (((n) & 7) << 3))

// ---------------- JAX Threefry-2x32 (partitionable) ----------------
__device__ __forceinline__ void tf2x32(uint32_t k0, uint32_t k1, uint32_t x0, uint32_t x1,
                                       uint32_t& o0, uint32_t& o1) {
  uint32_t ks2 = k0 ^ k1 ^ 0x1BD11BDAu;
  x0 += k0; x1 += k1;
#define TFR(r) { x0 += x1; x1 = (x1 << (r)) | (x1 >> (32 - (r))); x1 ^= x0; }
  TFR(13) TFR(15) TFR(26) TFR(6)
  x0 += k1;  x1 += ks2 + 1u;
  TFR(17) TFR(29) TFR(16) TFR(24)
  x0 += ks2; x1 += k0 + 2u;
  TFR(13) TFR(15) TFR(26) TFR(6)
  x0 += k0;  x1 += k1 + 3u;
  TFR(17) TFR(29) TFR(16) TFR(24)
  x0 += k1;  x1 += ks2 + 4u;
  TFR(13) TFR(15) TFR(26) TFR(6)
  x0 += ks2; x1 += k0 + 5u;
#undef TFR
  o0 = x0; o1 = x1;
}
__device__ __forceinline__ uint32_t tf_fold(uint32_t k0, uint32_t k1, uint32_t idx) {
  uint32_t a, b; tf2x32(k0, k1, 0u, idx, a, b); return a ^ b;
}

// ---------------- helpers ----------------
__device__ __forceinline__ unsigned short f2bf(float x) {
  uint32_t u = __float_as_uint(x);
  u += 0x7fffu + ((u >> 16) & 1u);
  return (unsigned short)(u >> 16);
}
__device__ __forceinline__ float dot4(f4 a, f4 b, float acc) {
  acc = fmaf(a.x, b.x, acc); acc = fmaf(a.y, b.y, acc);
  acc = fmaf(a.z, b.z, acc); acc = fmaf(a.w, b.w, acc);
  return acc;
}
__device__ __forceinline__ float dot_f4(const float* __restrict__ x, const float* __restrict__ w, int n4) {
  const f4* xv = (const f4*)x; const f4* wv = (const f4*)w;
  float s = 0.f;
#pragma unroll 8
  for (int k = 0; k < n4; ++k) s = dot4(xv[k], wv[k], s);
  return s;
}
__device__ __forceinline__ float sigm(float x) { return 1.f / (1.f + expf(-x)); }
__device__ __forceinline__ float wave_sum(float s) {
#pragma unroll
  for (int off = 32; off; off >>= 1) s += __shfl_xor(s, off, 64);
  return s;
}
__device__ __forceinline__ float wave_max(float s) {
#pragma unroll
  for (int off = 32; off; off >>= 1) s = fmaxf(s, __shfl_xor(s, off, 64));
  return s;
}

// sc-bit (agent-scope, L2-bypassing, NON-invalidating) loads/stores
__device__ __forceinline__ f4 load_sc_f4(const float* p) {
  union { f4 v; u64 u[2]; } r;
  r.u[0] = __hip_atomic_load((const u64*)p,     __ATOMIC_RELAXED, __HIP_MEMORY_SCOPE_AGENT);
  r.u[1] = __hip_atomic_load((const u64*)p + 1, __ATOMIC_RELAXED, __HIP_MEMORY_SCOPE_AGENT);
  return r.v;
}
__device__ __forceinline__ short8 load_sc_s8(const unsigned short* p) {
  union { short8 v; u64 u[2]; } r;
  r.u[0] = __hip_atomic_load((const u64*)p,     __ATOMIC_RELAXED, __HIP_MEMORY_SCOPE_AGENT);
  r.u[1] = __hip_atomic_load((const u64*)p + 1, __ATOMIC_RELAXED, __HIP_MEMORY_SCOPE_AGENT);
  return r.v;
}
__device__ __forceinline__ void store_sc_f(float* p, float v) {
  __hip_atomic_store(p, v, __ATOMIC_RELAXED, __HIP_MEMORY_SCOPE_AGENT);
}
__device__ __forceinline__ void store_sc_u64(u64* p, u64 v) {
  __hip_atomic_store(p, v, __ATOMIC_RELAXED, __HIP_MEMORY_SCOPE_AGENT);
}

// Poll with RELAXED loads (no buffer_inv); rare acquire hedge bounds staleness.
__device__ __forceinline__ void poll_ge(unsigned* p, unsigned epoch) {
  int spins = 0;
  while (__hip_atomic_load(p, __ATOMIC_RELAXED, __HIP_MEMORY_SCOPE_AGENT) < epoch) {
    __builtin_amdgcn_s_sleep(1);
    if (++spins >= (1 << 14)) {
      spins = 0;
      (void)__hip_atomic_load(p, __ATOMIC_ACQUIRE, __HIP_MEMORY_SCOPE_AGENT);
    }
  }
}

// Full barrier (two-hop). fence=true adds release fence (wbl2) — prologue only.
__device__ __forceinline__ void grid_sync_full(unsigned* slotsB, unsigned ep, int tid, int bid,
                                               bool fence) {
  unsigned* go = slotsB + NB * 16;
  __syncthreads();
  if (fence && tid == 0) __builtin_amdgcn_fence(__ATOMIC_RELEASE, "agent");
  if (bid == 0) {
    if (tid < NB) {
      if (tid == 0)
        __hip_atomic_store(slotsB, ep, __ATOMIC_RELAXED, __HIP_MEMORY_SCOPE_AGENT);
      poll_ge(slotsB + tid * 16, ep);
    }
    __syncthreads();
    if (tid == 0)
      __hip_atomic_store(go, ep, __ATOMIC_RELAXED, __HIP_MEMORY_SCOPE_AGENT);
  } else {
    if (tid == 0) {
      __hip_atomic_store(slotsB + bid * 16, ep, __ATOMIC_RELAXED, __HIP_MEMORY_SCOPE_AGENT);
      poll_ge(go, ep);
    }
    __syncthreads();
  }
}

// Partial barrier: blocks 0..31 are the producers; everyone waits on their 32 slots (1 hop).
__device__ __forceinline__ void grid_sync_partial(unsigned* slotsA, unsigned ep, int tid, int bid) {
  __syncthreads();                    // drains this block's sc stores (vmcnt)
  if (bid < 32 && tid == 0)
    __hip_atomic_store(slotsA + bid * 16, ep, __ATOMIC_RELAXED, __HIP_MEMORY_SCOPE_AGENT);
  if (tid < 32) poll_ge(slotsA + tid * 16, ep);
  __syncthreads();
}

// projection: out[m, tout] for one batch; K = 1536 = [dh 1024 | actx 512] (cross-block -> sc loads)
__device__ __forceinline__ void project(int tid, int b,
    const float* __restrict__ dhb, const float* __restrict__ axb,
    const float* __restrict__ proj_w, const float* __restrict__ proj_b,
    float* __restrict__ out, int tout) {
  const int wid = tid >> 6, l = tid & 63;
  f4 xp[6];
#pragma unroll
  for (int c = 0; c < 6; ++c) {
    const int kf = l + 64 * c;
    const float* p = (c < 4) ? dhb + kf * 4 : axb + (kf - 256) * 4;
    xp[c] = load_sc_f4(p);
  }
#pragma unroll
  for (int mi = 0; mi < 5; ++mi) {
    const int m = wid * 5 + mi;
    const f4* wr = (const f4*)(proj_w + (size_t)m * 1536);
    float s = 0.f;
#pragma unroll
    for (int c = 0; c < 6; ++c) s = dot4(wr[l + 64 * c], xp[c], s);
    s = wave_sum(s);
    if (l == 0) out[(size_t)b * 16000 + m * 200 + tout] = s + proj_b[m];
  }
}

__global__ __launch_bounds__(TPB, 4) void decoder_persistent_kernel(
    const float* __restrict__ memory, const float* __restrict__ dec_inp,
    const int* __restrict__ mem_len,
    const float* __restrict__ pw1, const float* __restrict__ pw2,
    const float* __restrict__ a_wih, const float* __restrict__ a_whh, const float* __restrict__ a_b,
    const float* __restrict__ d_wih, const float* __restrict__ d_whh, const float* __restrict__ d_b,
    const float* __restrict__ proj_w, const float* __restrict__ proj_b,
    const float* __restrict__ query_w, const float* __restrict__ memory_w,
    const float* __restrict__ v_w, const float* __restrict__ conv_w, const float* __restrict__ ldw,
    float* __restrict__ out, float* __restrict__ wsf) {
  __shared__ __align__(16) unsigned short Wc_sh[16 * 2568];  // 82,176 B (swizzled rows, K=[actx|ah|dh])
  __shared__ __align__(16) unsigned short Wa_sh[16 * 1800];  // 57,600 B (swizzled rows, K=[dec|actx|ah])
  __shared__ __align__(16) float scr[4096];                  // 16,384 B scratch union

  unsigned* slotsB = (unsigned*)wsf;
  unsigned* slotsA = (unsigned*)wsf + O_SLOTA;
  const int tid = threadIdx.x;
  const int bid = blockIdx.x;
  const int jbase = bid * 4;
  unsigned ep1 = 0, ep2 = 0;

  unsigned short* xU    = (unsigned short*)(wsf + O_XU);
  unsigned short* decfr = (unsigned short*)(wsf + O_DECFR);
  unsigned short* ldwbf = (unsigned short*)(wsf + O_LDWBF);
  float* convwt = wsf + O_CONVWT;
  float* pmem   = wsf + O_PMEM;

  // ================= PROLOGUE =================
  // P0a: prenet -> decfr bf16 frag layout [tt][k8][b][e]
  {
    uint32_t d00, d01, d10, d11;
    tf2x32(0u, 42u, 0u, 0u, d00, d01);
    tf2x32(0u, 42u, 0u, 1u, d10, d11);
    const int s = tid >> 8, st = tid & 255;
    float* xin = scr + s * 336;
    float* h1  = scr + s * 336 + 80;
    for (int base = bid * 4; base < 3200; base += NB * 4) {
      const int task = base + s;
      const int tt = task >> 4, b = task & 15;
      if (st < 80) xin[st] = (tt == 0) ? 0.f : dec_inp[(size_t)b * 16000 + st * 200 + (tt - 1)];
      __syncthreads();
      float acc = 0.f;
      const float* w1r = pw1 + st * 80;
#pragma unroll 4
      for (int mm = 0; mm < 80; ++mm) acc = fmaf(xin[mm], w1r[mm], acc);
      acc = fmaxf(acc, 0.f);
      const uint32_t idx = (uint32_t)task * 256u + (uint32_t)st;
      acc = (tf_fold(d00, d01, idx) >> 31) ? 0.f : acc * 2.f;
      h1[st] = acc;
      __syncthreads();
      float acc2 = 0.f;
      const float* w2r = pw2 + st * 256;
#pragma unroll 4
      for (int pp = 0; pp < 256; ++pp) acc2 = fmaf(h1[pp], w2r[pp], acc2);
      acc2 = fmaxf(acc2, 0.f);
      acc2 = (tf_fold(d10, d11, idx) >> 31) ? 0.f : acc2 * 2.f;
      decfr[(size_t)tt * 4096 + (st >> 3) * 128 + b * 8 + (st & 7)] = f2bf(acc2);
      __syncthreads();
    }
  }
  // P0b: pmem = memory @ memory_w.T
  {
    const int s = tid >> 7, st = tid & 127;
    for (int base = bid * 8; base < 4096; base += NB * 8) {
      const int task = base + s;
      pmem[(size_t)task * 128 + st] =
          dot_f4(memory + (size_t)task * 512, memory_w + (size_t)st * 512, 128);
    }
  }
  // P0c: weights -> LDS bf16, swizzled. Wc K-layout = [actx(512) | ah(1024) | dh(1024)].
  for (int n = 0; n < 16; ++n) {
    const int g = n & 3, jl = n >> 2;
    const int row = g * 1024 + jbase + jl;
    const float* wC1 = d_wih + (size_t)row * 1536;   // [ah 1024 | actx 512]
    const float* wC2 = d_whh + (size_t)row * 1024;   // dh
    for (int k = tid; k < 2560; k += TPB) {
      float v;
      if (k < 512)       v = wC1[1024 + k];          // actx
      else if (k < 1536) v = wC1[k - 512];           // ah
      else               v = wC2[k - 1536];          // dh
      Wc_sh[n * 2568 + SWZ(n, k)] = f2bf(v);
    }
    const float* wA1 = a_wih + (size_t)row * 768;    // [dec 256 | actx 512]
    const float* wA2 = a_whh + (size_t)row * 1024;   // ah
    for (int k = tid; k < 1792; k += TPB)
      Wa_sh[n * 1800 + SWZ(n, k)] = f2bf(k < 768 ? wA1[k] : wA2[k - 768]);
  }
  // P0d: small weight copies
  if (bid == 0) for (int i = tid; i < 4096; i += TPB) ldwbf[i] = f2bf(ldw[i]);
  if (bid == 1) for (int i = tid; i < 1984; i += TPB) {
    const int o = i & 31, ck = i >> 5;
    convwt[ck * 32 + o] = conv_w[o * 62 + ck];
  }
  ++ep2; grid_sync_full(slotsB, ep2, tid, bid, true);   // fence: publish plain-stored decfr/pmem

  // ================= MAIN LOOP (t = -1 runs A(0) only) =================
  for (int t = -1; t < 200; ++t) {
    if (t >= 0) {
      // ---- P1P2: full attention (blocks 0..15) | proj t-1 (16..31) ----
      if (bid < 16) {
        const int b = bid;
        float* awst  = scr;              // [2][160]
        float* q_s   = scr + 320;        // [128]
        float* e_red = scr + 448;        // [2][128]
        unsigned short* loc_s = (unsigned short*)(scr + 704);  // [128][40] bf16
        float* red8  = scr;              // reuse
        float* awv_s = scr + 16;
        float* part  = scr + 144;
        if (tid < 320) {
          const int c2 = tid / 160, j = tid % 160, p = 113 + j;
          awst[c2 * 160 + j] = (p < 256) ? wsf[(c2 ? O_AWC : O_AW) + b * 256 + p] : 0.f;
        }
        __syncthreads();
        // conv
        {
          const int ttl = tid >> 3, o0 = (tid & 7) * 4;
          float l0 = 0.f, l1 = 0.f, l2 = 0.f, l3 = 0.f;
#pragma unroll
          for (int c2 = 0; c2 < 2; ++c2) {
            const float* src = awst + c2 * 160 + ttl;
            const float* wp  = convwt + (c2 * 31) * 32 + o0;
#pragma unroll
            for (int k = 0; k < 31; ++k) {
              const float v = src[k];
              const f4 wv = *(const f4*)(wp + k * 32);
              l0 = fmaf(v, wv.x, l0); l1 = fmaf(v, wv.y, l1);
              l2 = fmaf(v, wv.z, l2); l3 = fmaf(v, wv.w, l3);
            }
          }
          unsigned short* lp = loc_s + ttl * 40 + o0;
          lp[0] = f2bf(l0); lp[1] = f2bf(l1); lp[2] = f2bf(l2); lp[3] = f2bf(l3);
        }
        // query: ah cross-block -> sc loads; query_w plain (L2-resident)
        {
          const int w = tid >> 6, l = tid & 63;
          f4 xq[4];
#pragma unroll
          for (int c = 0; c < 4; ++c)
            xq[c] = load_sc_f4(wsf + O_AH + b * 1024 + (l + 64 * c) * 4);
#pragma unroll
          for (int i = 0; i < 8; ++i) {
            const int a = w * 8 + i;
            const f4* wr = (const f4*)(query_w + (size_t)a * 1024);
            float s = 0.f;
#pragma unroll
            for (int c = 0; c < 4; ++c) s = dot4(wr[l + 64 * c], xq[c], s);
            s = wave_sum(s);
            if (l == 0) q_s[a] = s;
          }
        }
        __syncthreads();
        // dense via MFMA
        {
          const int w = tid >> 6, l = tid & 63, q = l >> 4, c = l & 15;
          const int ttile = w >> 1;
          const short8 af = *(const short8*)(loc_s + (ttile * 16 + c) * 40 + q * 8);
          float eacc[4] = {0.f, 0.f, 0.f, 0.f};
#pragma unroll
          for (int at = 0; at < 4; ++at) {
            const int a = ((w & 1) * 4 + at) * 16 + c;
            const short8 bf = *(const short8*)(ldwbf + a * 32 + q * 8);
            f32x4 d = {0.f, 0.f, 0.f, 0.f};
            d = __builtin_amdgcn_mfma_f32_16x16x32_bf16(af, bf, d, 0, 0, 0);
            const float qa = q_s[a];
            const float vv = v_w[a];
#pragma unroll
            for (int r = 0; r < 4; ++r) {
              const int tt = 128 + ttile * 16 + 4 * q + r;
              float s = d[r] + qa + pmem[(size_t)(b * 256 + tt) * 128 + a];
              s = fminf(20.f, fmaxf(-20.f, s));
              eacc[r] = fmaf(tanhf(s), vv, eacc[r]);
            }
          }
#pragma unroll
          for (int r = 0; r < 4; ++r) {
            float e = eacc[r];
            e += __shfl_xor(e, 1, 64); e += __shfl_xor(e, 2, 64);
            e += __shfl_xor(e, 4, 64); e += __shfl_xor(e, 8, 64);
            if (c == 0) e_red[(w & 1) * 128 + ttile * 16 + 4 * q + r] = e;
          }
        }
        __syncthreads();
        // softmax (mask: tt < len -> -inf)
        const int lenb = mem_len[b];
        float e = 0.f, p = 0.f; bool live = false;
        if (tid < 128) {
          const int tt = 128 + tid;
          live = tt >= lenb;
          e = e_red[tid] + e_red[128 + tid];
          float m = live ? e : -3.4e38f;
          m = wave_max(m);
          if ((tid & 63) == 0) red8[tid >> 6] = m;
        }
        __syncthreads();
        const float mx = fmaxf(red8[0], red8[1]);
        if (tid < 128) {
          p = live ? expf(e - mx) : 0.f;
          float z = wave_sum(p);
          if ((tid & 63) == 0) red8[2 + (tid >> 6)] = z;
        }
        __syncthreads();
        if (tid < 128) {
          const float z = red8[2] + red8[3];
          const float awv = live ? p / z : 0.f;
          awv_s[tid] = awv;
          wsf[O_AW + b * 256 + 128 + tid] = awv;            // private
          if (live) wsf[O_AWC + b * 256 + 128 + tid] += awv;
        }
        __syncthreads();
        // actx = aw @ memory
        {
          const int th = tid >> 9, e0 = tid & 511;
          float a = 0.f;
#pragma unroll 4
          for (int j = 0; j < 64; ++j) {
            const int tt = 128 + th * 64 + j;
            a = fmaf(awv_s[th * 64 + j], memory[((size_t)(b * 256 + tt)) * 512 + e0], a);
          }
          part[th * 512 + e0] = a;
        }
        __syncthreads();
        if (tid < 512) {
          const float a = part[tid] + part[512 + tid];
          store_sc_f(wsf + O_ACTX + (t & 1) * 8192 + b * 512 + tid, a);   // write-through
        }
        if (tid < 64) {
          // pack 8 bf16 -> 2 u64 write-through stores (xU actx slots, k8 = tid)
          u64 lo = 0, hi = 0;
#pragma unroll
          for (int e2 = 0; e2 < 4; ++e2)
            lo |= (u64)f2bf(part[tid * 8 + e2] + part[512 + tid * 8 + e2]) << (16 * e2);
#pragma unroll
          for (int e2 = 4; e2 < 8; ++e2)
            hi |= (u64)f2bf(part[tid * 8 + e2] + part[512 + tid * 8 + e2]) << (16 * (e2 - 4));
          u64* dst = (u64*)(xU + (t & 1) * XU_PAR + tid * 128 + b * 8);
          store_sc_u64(dst + 0, lo);
          store_sc_u64(dst + 1, hi);
        }
      } else if (bid < 32 && t > 0) {
        const int b = bid - 16;
        project(tid, b, wsf + O_DH + b * 1024,
                wsf + O_ACTX + ((t - 1) & 1) * 8192 + b * 512, proj_w, proj_b, out, t - 1);
      }
      ++ep1; grid_sync_partial(slotsA, ep1, tid, bid);   // 1-hop; no fence
    }

    // ---- P3: C(t) MFMA (waves 0..7) + A(t+1) MFMA (waves 8..15) + pointwise ----
    {
      const int rp = t & 1;
      const unsigned short* xUr = xU + rp * XU_PAR;
      unsigned short* xUw = xU + (rp ^ 1) * XU_PAR;
      float* redC = scr;          // [8][256]
      float* redA = scr + 2048;   // [8][256]
      const int w = tid >> 6, l = tid & 63;
      const int q = l >> 4, c = l & 15;
      if (w < 8) {
        if (t >= 0) {
          f32x4 acc = {0.f, 0.f, 0.f, 0.f};
#pragma unroll
          for (int i = 0; i < 10; ++i) {
            const int k32 = w * 10 + i;                        // [actx|ah|dh]
            const short8 af = load_sc_s8(xUr + k32 * 512 + l * 8);
            const short8 bf = *(const short8*)(Wc_sh + c * 2568 + SWZ(c, q * 8 + k32 * 32));
            acc = __builtin_amdgcn_mfma_f32_16x16x32_bf16(af, bf, acc, 0, 0, 0);
          }
#pragma unroll
          for (int r = 0; r < 4; ++r) redC[w * 256 + (4 * q + r) * 16 + c] = acc[r];
        }
      } else {
        if (t < 199) {
          const unsigned short* dfr = decfr + (size_t)(t + 1) * 4096;
          f32x4 acc = {0.f, 0.f, 0.f, 0.f};
#pragma unroll
          for (int i = 0; i < 7; ++i) {
            const int k32 = (w - 8) * 7 + i;                   // [dec|actx|ah]
            short8 af;
            if (k32 < 8) af = *(const short8*)(dfr + k32 * 512 + l * 8);   // read-only, cached
            else         af = load_sc_s8(xUr + (k32 - 8) * 512 + l * 8);   // cross-block state
            const short8 bf = *(const short8*)(Wa_sh + c * 1800 + SWZ(c, q * 8 + k32 * 32));
            acc = __builtin_amdgcn_mfma_f32_16x16x32_bf16(af, bf, acc, 0, 0, 0);
          }
#pragma unroll
          for (int r = 0; r < 4; ++r) redA[(w - 8) * 256 + (4 * q + r) * 16 + c] = acc[r];
        }
      }
      __syncthreads();
      if (tid < 64) {
        if (t >= 0) {            // C pointwise -> dh(t)
          const int b = tid >> 2, jl = tid & 3, J = jbase + jl;
          float gv[4];
#pragma unroll
          for (int g = 0; g < 4; ++g) {
            float s = d_b[g * 1024 + J];
#pragma unroll
            for (int w2 = 0; w2 < 8; ++w2) s += redC[w2 * 256 + b * 16 + (jl * 4 + g)];
            gv[g] = s;
          }
          const int bi = b * 1024 + J;
          const float c2v = sigm(gv[1]) * wsf[O_DC + bi] + sigm(gv[0]) * tanhf(gv[2]);
          wsf[O_DC + bi] = c2v;                              // private
          const float h = sigm(gv[3]) * tanhf(c2v);
          store_sc_f(wsf + O_DH + bi, h);                    // write-through
          const unsigned hb = f2bf(h);
          const int lb = tid & ~3;
          const unsigned v0 = __shfl(hb, lb + 0, 64);
          const unsigned v1 = __shfl(hb, lb + 1, 64);
          const unsigned v2 = __shfl(hb, lb + 2, 64);
          const unsigned v3 = __shfl(hb, lb + 3, 64);
          if (jl == 0) {
            const u64 pk = (u64)v0 | ((u64)v1 << 16) | ((u64)v2 << 32) | ((u64)v3 << 48);
            store_sc_u64((u64*)(xUw + (192 + (jbase >> 3)) * 128 + b * 8 + (jbase & 7)), pk);
          }
        }
      } else if (tid < 128) {
        if (t < 199) {           // A(t+1) pointwise -> ah(t+1)
          const int t2 = tid - 64;
          const int b = t2 >> 2, jl = t2 & 3, J = jbase + jl;
          float gv[4];
#pragma unroll
          for (int g = 0; g < 4; ++g) {
            float s = a_b[g * 1024 + J];
#pragma unroll
            for (int w2 = 0; w2 < 8; ++w2) s += redA[w2 * 256 + b * 16 + (jl * 4 + g)];
            gv[g] = s;
          }
          const int bi = b * 1024 + J;
          const float c2v = sigm(gv[1]) * wsf[O_AC + bi] + sigm(gv[0]) * tanhf(gv[2]);
          wsf[O_AC + bi] = c2v;                              // private
          const float h = sigm(gv[3]) * tanhf(c2v);
          store_sc_f(wsf + O_AH + bi, h);                    // write-through
          const unsigned hb = f2bf(h);
          const int lb = t2 & ~3;
          const unsigned v0 = __shfl(hb, lb + 0, 64);
          const unsigned v1 = __shfl(hb, lb + 1, 64);
          const unsigned v2 = __shfl(hb, lb + 2, 64);
          const unsigned v3 = __shfl(hb, lb + 3, 64);
          if (jl == 0) {
            const u64 pk = (u64)v0 | ((u64)v1 << 16) | ((u64)v2 << 32) | ((u64)v3 << 48);
            store_sc_u64((u64*)(xUw + (64 + (jbase >> 3)) * 128 + b * 8 + (jbase & 7)), pk);
          }
        }
      }
    }
    ++ep2; grid_sync_full(slotsB, ep2, tid, bid, false);   // no fence: all shared data write-through
  }

  // ---- final projection t = 199 (actx parity 1) ----
  if (bid >= 16 && bid < 32) {
    const int b = bid - 16;
    project(tid, b, wsf + O_DH + b * 1024, wsf + O_ACTX + 8192 + b * 512,
            proj_w, proj_b, out, 199);
  }
}

extern "C" void kernel_launch(void* const* d_in, const int* in_sizes, int n_in,
                              void* d_out, int out_size, void* d_ws, size_t ws_size,
                              hipStream_t stream) {
  (void)in_sizes; (void)n_in; (void)out_size; (void)ws_size;
  const float* memory   = (const float*)d_in[0];
  const float* dec_inp  = (const float*)d_in[1];
  const int*   mem_len  = (const int*)d_in[2];
  const float* pw1      = (const float*)d_in[3];
  const float* pw2      = (const float*)d_in[4];
  const float* a_wih    = (const float*)d_in[5];
  const float* a_whh    = (const float*)d_in[6];
  const float* a_b      = (const float*)d_in[7];
  const float* d_wih    = (const float*)d_in[8];
  const float* d_whh    = (const float*)d_in[9];
  const float* d_b      = (const float*)d_in[10];
  const float* proj_w   = (const float*)d_in[11];
  const float* proj_b   = (const float*)d_in[12];
  const float* query_w  = (const float*)d_in[13];
  const float* memory_w = (const float*)d_in[14];
  const float* v_w      = (const float*)d_in[15];
  const float* conv_w   = (const float*)d_in[16];
  const float* ldw      = (const float*)d_in[17];

  hipMemsetAsync(d_ws, 0, ZERO_BYTES, stream);
  decoder_persistent_kernel<<<NB, TPB, 0, stream>>>(
      memory, dec_inp, mem_len, pw1, pw2, a_wih, a_whh, a_b,
      d_wih, d_whh, d_b, proj_w, proj_b, query_w, memory_w, v_w, conv_w, ldw,
      (float*)d_out, (float*)d_ws);
}